// Round 10
// baseline (512.790 us; speedup 1.0000x reference)
//
#include <hip/hip_runtime.h>
#include <hip/hip_fp16.h>

#define N_NODES 100000
#define N_EDGES 1600000
#define DIM 128
#define NC 40

#define BUCKET_SHIFT 7
#define BUCKET_NODES 128
#define NBUCKET ((N_NODES + BUCKET_NODES - 1) / BUCKET_NODES)   // 782
#define NBIN 1024
#define EPB 4096
#define NBLK_FILL ((N_EDGES + EPB - 1) / EPB)                   // 391

typedef _Float16 f16x8 __attribute__((ext_vector_type(8)));
typedef float f32x4 __attribute__((ext_vector_type(4)));

// ---------------- CSR hist + x->fp16 + zero rows + W pack (fused; pack rides on extra blocks) ------
__global__ __launch_bounds__(256) void k_hist_cvt(const int2* __restrict__ ei, int* __restrict__ deg,
                                                  const float* __restrict__ x, __half* __restrict__ xh,
                                                  __half* __restrict__ y,
                                                  const float* __restrict__ W1a, const float* __restrict__ W1b,
                                                  const float* __restrict__ W2a,
                                                  _Float16* __restrict__ Pa, _Float16* __restrict__ Pb,
                                                  _Float16* __restrict__ Pc) {
    int bid = blockIdx.x, tid = threadIdx.x;
    if (bid >= N_EDGES / 256) {
        // ---- weight packing: frag chunk c: k = 32*kt + (lane>>4)*8 + j, n = 16*nt + (lane&15) ----
        int pb = bid - N_EDGES / 256;           // 0..18
        if (pb < 16) {
            const float* W = (pb < 8) ? W1a : W1b;
            _Float16* P = (pb < 8) ? Pa : Pb;
            int t = (pb & 7) * 256 + tid;       // 0..2047
            int l = t & 63, nt = (t >> 6) & 7, kt = t >> 9;
            int n = nt * 16 + (l & 15);
            int kb = kt * 32 + (l >> 4) * 8;
            #pragma unroll
            for (int j = 0; j < 8; ++j)
                P[(size_t)t * 8 + j] = (_Float16)W[(size_t)(kb + j) * DIM + n];
        } else {
            int t = (pb - 16) * 256 + tid;      // 0..767
            if (t < 768) {
                int l = t & 63, u = t >> 6;
                int nt = u % 3, kt = u / 3;
                int n = nt * 16 + (l & 15);
                int kb = kt * 32 + (l >> 4) * 8;
                #pragma unroll
                for (int j = 0; j < 8; ++j) {
                    float wv = (n < NC) ? W2a[(size_t)(kb + j) * NC + n] : 0.f;
                    Pc[(size_t)t * 8 + j] = (_Float16)wv;
                }
            }
        }
        return;
    }
    int i = bid * 256 + tid;                    // < N_EDGES exactly
    if (bid == 0) {
        if (tid < 16) ((uint4*)xh)[(size_t)N_NODES * (DIM / 8) + tid] = (uint4){0, 0, 0, 0};
        else if (tid < 21) ((uint4*)y)[(size_t)N_NODES * 5 + tid - 16] = (uint4){0, 0, 0, 0};
    }
    int2 e = ei[i];
    atomicAdd(&deg[e.y + 1], 1);
    float4 v0 = ((const float4*)x)[(size_t)i * 2];
    float4 v1 = ((const float4*)x)[(size_t)i * 2 + 1];
    __half2 h01 = __float22half2_rn(make_float2(v0.x, v0.y));
    __half2 h23 = __float22half2_rn(make_float2(v0.z, v0.w));
    __half2 h45 = __float22half2_rn(make_float2(v1.x, v1.y));
    __half2 h67 = __float22half2_rn(make_float2(v1.z, v1.w));
    uint4 o;
    o.x = *(unsigned*)&h01; o.y = *(unsigned*)&h23;
    o.z = *(unsigned*)&h45; o.w = *(unsigned*)&h67;
    ((uint4*)xh)[i] = o;
}

#define SCAN_N (N_NODES + 1)
#define SCAN_T 256
#define SCAN_PER 32
#define SCAN_CHUNK (SCAN_T * SCAN_PER)                      // 8192
#define SCAN_NB ((SCAN_N + SCAN_CHUNK - 1) / SCAN_CHUNK)    // 13

// single-kernel scan: block b re-sums deg[0..b*8192) for its offset (raw deg is never overwritten;
// scanned output goes to rp), scans its chunk, emits rp + bucket bases.
__global__ __launch_bounds__(SCAN_T) void k_scan(const int* __restrict__ deg, int* __restrict__ rp,
                                                 int* __restrict__ bcur) {
    __shared__ int red[SCAN_T / 64];
    __shared__ int wtot[SCAN_T / 64];
    int t = threadIdx.x, lane = t & 63, wid = t >> 6;
    int cbase = blockIdx.x * SCAN_CHUNK;

    int off = 0;
    for (int i = t; i < cbase; i += SCAN_T) off += deg[i];
    #pragma unroll
    for (int d = 32; d >= 1; d >>= 1) off += __shfl_xor(off, d, 64);
    if (lane == 0) red[wid] = off;
    __syncthreads();
    off = red[0] + red[1] + red[2] + red[3];

    int base = cbase + t * SCAN_PER;
    int v[SCAN_PER];
    int run = 0;
    #pragma unroll
    for (int j = 0; j < SCAN_PER; ++j) {
        int idx = base + j;
        int xv = (idx < SCAN_N) ? deg[idx] : 0;
        run += xv;
        v[j] = run;
    }
    int incl = run;
    #pragma unroll
    for (int d = 1; d < 64; d <<= 1) {
        int u = __shfl_up(incl, d, 64);
        if (lane >= d) incl += u;
    }
    if (lane == 63) wtot[wid] = incl;
    __syncthreads();
    int add = incl - run + off;
    for (int w = 0; w < wid; ++w) add += wtot[w];
    #pragma unroll
    for (int j = 0; j < SCAN_PER; ++j) {
        int idx = base + j;
        if (idx < SCAN_N) {
            int val = v[j] + add;
            rp[idx] = val;
            if ((idx & (BUCKET_NODES - 1)) == 0 && idx < N_NODES) bcur[idx >> BUCKET_SHIFT] = val;
        }
    }
}

// ---------------- binfill: LDS counting-sort edges by 128-node bucket ----------------
__global__ __launch_bounds__(256) void k_binfill(const int2* __restrict__ ei, int* __restrict__ bcur,
                                                 int* __restrict__ stg) {
    __shared__ int hist[NBIN];
    __shared__ int offs[NBIN];
    __shared__ int gbase[NBIN];
    __shared__ int cnt[NBIN];
    __shared__ int lds[EPB];
    __shared__ int wt[4];
    int t = threadIdx.x;
    int e0 = blockIdx.x * EPB;
    int bec = N_EDGES - e0; if (bec > EPB) bec = EPB;

    #pragma unroll
    for (int j = 0; j < NBIN / 256; ++j) { hist[t + j * 256] = 0; cnt[t + j * 256] = 0; }
    __syncthreads();

    for (int k = 0; k < EPB / 256; ++k) {
        int i = e0 + t + k * 256;
        if (i < N_EDGES) {
            int2 e = ei[i];
            atomicAdd(&hist[e.y >> BUCKET_SHIFT], 1);
        }
    }
    __syncthreads();

    int lane = t & 63, w = t >> 6;
    int h[4], p = 0;
    #pragma unroll
    for (int j = 0; j < 4; ++j) { h[j] = hist[t * 4 + j]; p += h[j]; }
    int inc = p;
    #pragma unroll
    for (int d = 1; d < 64; d <<= 1) {
        int u = __shfl_up(inc, d, 64);
        if (lane >= d) inc += u;
    }
    if (lane == 63) wt[w] = inc;
    __syncthreads();
    int add = inc - p;
    for (int k = 0; k < w; ++k) add += wt[k];
    int run = add;
    #pragma unroll
    for (int j = 0; j < 4; ++j) { offs[t * 4 + j] = run; run += h[j]; }
    __syncthreads();

    #pragma unroll
    for (int j = 0; j < 4; ++j) {
        int b = t * 4 + j;
        if (b < NBUCKET && h[j] > 0) gbase[b] = atomicAdd(&bcur[b], h[j]);
    }
    __syncthreads();

    for (int k = 0; k < EPB / 256; ++k) {
        int i = e0 + t + k * 256;
        if (i < N_EDGES) {
            int2 e = ei[i];
            int b = e.y >> BUCKET_SHIFT;
            int pos = offs[b] + atomicAdd(&cnt[b], 1);
            lds[pos] = e.x | ((e.y & (BUCKET_NODES - 1)) << 17);
        }
    }
    __syncthreads();

    for (int i = t; i < bec; i += 256) {
        int lo = 0, hi = NBIN - 1;
        while (lo < hi) { int mid = (lo + hi + 1) >> 1; if (offs[mid] <= i) lo = mid; else hi = mid - 1; }
        stg[gbase[lo] + (i - offs[lo])] = lds[i];
    }
}

// ---------------- per-bucket CSR fill ----------------
__global__ __launch_bounds__(256) void k_csr_local(const int* __restrict__ rp, const int* __restrict__ stg,
                                                   int* __restrict__ csr) {
    __shared__ int cur[BUCKET_NODES];
    int t = threadIdx.x, b = blockIdx.x;
    int n0 = b * BUCKET_NODES;
    int nn = N_NODES - n0; if (nn > BUCKET_NODES) nn = BUCKET_NODES;
    if (t < nn) cur[t] = rp[n0 + t];
    __syncthreads();
    int beg = rp[n0], end = rp[n0 + nn];
    for (int i = beg + t; i < end; i += 256) {
        int e = stg[i];
        int dl = (e >> 17) & (BUCKET_NODES - 1);
        int pos = atomicAdd(&cur[dl], 1);
        csr[pos] = e & 0x1FFFF;
    }
}

// ---------------- fused gather1 + 3-GEMM MLP: y = relu(relu((x+seg)@W1a+b1a)@W1b+b1b)@W2a -------
// Wave w gathers its 16 nodes into LDS rows [16w,16w+16) (2 rows per dwordx2 via half-waves),
// then runs the MFMA chain on ITS OWN rows only -> no __syncthreads, single LDS buffer.
__global__ __launch_bounds__(256) void k_gmlp(const __half* __restrict__ xh, const int* __restrict__ rp,
    const int* __restrict__ csr,
    const _Float16* __restrict__ Pa, const _Float16* __restrict__ Pb, const _Float16* __restrict__ Pc,
    const float* __restrict__ b1a, const float* __restrict__ b1b, __half* __restrict__ y) {
    __shared__ _Float16 A[64][136];   // +8 pad; single buffer reused across all 3 GEMMs
    int t = threadIdx.x, w = t >> 6, l = t & 63;
    int half = l >> 5, sub = l & 31;
    size_t row0 = (size_t)blockIdx.x * 64;
    const uint2* x2 = (const uint2*)xh;

    // ---- gather phase: 16 nodes per wave ----
    for (int k16 = 0; k16 < 16; ++k16) {
        int rloc = w * 16 + k16;
        size_t n = row0 + rloc;
        float4 acc = {0.f, 0.f, 0.f, 0.f};
        if (n < N_NODES) {                      // wave-uniform branch
            uint2 sv;
            if (half == 0) sv = x2[n * 32 + sub];
            int i0 = rp[n], e = rp[n + 1];
            int niter = (e - i0 + 7) >> 3;
            for (int k = 0; k < niter; ++k) {
                int base = i0 + k * 8;
                int s[4];
                #pragma unroll
                for (int u = 0; u < 4; ++u) {
                    int idx = base + u * 2 + half;
                    s[u] = (idx < e) ? csr[idx] : N_NODES;   // zero row
                }
                uint2 v[4];
                #pragma unroll
                for (int u = 0; u < 4; ++u) v[u] = x2[(size_t)s[u] * 32 + sub];
                #pragma unroll
                for (int u = 0; u < 4; ++u) {
                    __half2 h0, h1;
                    *(unsigned*)&h0 = v[u].x; *(unsigned*)&h1 = v[u].y;
                    float2 f0 = __half22float2(h0), f1 = __half22float2(h1);
                    acc.x += f0.x; acc.y += f0.y; acc.z += f1.x; acc.w += f1.y;
                }
            }
            acc.x += __shfl_xor(acc.x, 32);
            acc.y += __shfl_xor(acc.y, 32);
            acc.z += __shfl_xor(acc.z, 32);
            acc.w += __shfl_xor(acc.w, 32);
            if (half == 0) {
                __half2 h0, h1;
                *(unsigned*)&h0 = sv.x; *(unsigned*)&h1 = sv.y;
                float2 f0 = __half22float2(h0), f1 = __half22float2(h1);
                acc.x += f0.x; acc.y += f0.y; acc.z += f1.x; acc.w += f1.y;
            }
        }
        if (half == 0) {
            __half2 o0 = __float22half2_rn(make_float2(acc.x, acc.y));
            __half2 o1 = __float22half2_rn(make_float2(acc.z, acc.w));
            unsigned u0 = *(unsigned*)&o0, u1 = *(unsigned*)&o1;
            unsigned* dst = (unsigned*)&A[rloc][sub * 4];
            dst[0] = u0; dst[1] = u1;
        }
    }
    // no barrier: each wave only reads rows it wrote

    int arow = 16 * w + (l & 15);
    int kq = (l >> 4) * 8;
    int crow = 16 * w + (l >> 4) * 4;
    int ccol = l & 15;
    f16x8 af[4];
    f32x4 acc[8];

    // ---- GEMM1: A @ W1a + b1a, relu -> A ----
    #pragma unroll
    for (int kt = 0; kt < 4; ++kt) af[kt] = *(const f16x8*)&A[arow][kt * 32 + kq];
    #pragma unroll
    for (int nt = 0; nt < 8; ++nt) {
        float b = b1a[nt * 16 + ccol];
        acc[nt] = (f32x4){b, b, b, b};
    }
    #pragma unroll
    for (int nt = 0; nt < 8; ++nt)
        #pragma unroll
        for (int kt = 0; kt < 4; ++kt) {
            f16x8 bf = *(const f16x8*)(Pa + ((size_t)((kt << 3) + nt) * 64 + l) * 8);
            acc[nt] = __builtin_amdgcn_mfma_f32_16x16x32_f16(af[kt], bf, acc[nt], 0, 0, 0);
        }
    #pragma unroll
    for (int nt = 0; nt < 8; ++nt)
        #pragma unroll
        for (int r = 0; r < 4; ++r)
            A[crow + r][nt * 16 + ccol] = (_Float16)fmaxf(acc[nt][r], 0.f);

    // ---- GEMM2: A @ W1b + b1b, relu -> A ----
    #pragma unroll
    for (int kt = 0; kt < 4; ++kt) af[kt] = *(const f16x8*)&A[arow][kt * 32 + kq];
    #pragma unroll
    for (int nt = 0; nt < 8; ++nt) {
        float b = b1b[nt * 16 + ccol];
        acc[nt] = (f32x4){b, b, b, b};
    }
    #pragma unroll
    for (int nt = 0; nt < 8; ++nt)
        #pragma unroll
        for (int kt = 0; kt < 4; ++kt) {
            f16x8 bf = *(const f16x8*)(Pb + ((size_t)((kt << 3) + nt) * 64 + l) * 8);
            acc[nt] = __builtin_amdgcn_mfma_f32_16x16x32_f16(af[kt], bf, acc[nt], 0, 0, 0);
        }
    #pragma unroll
    for (int nt = 0; nt < 8; ++nt)
        #pragma unroll
        for (int r = 0; r < 4; ++r)
            A[crow + r][nt * 16 + ccol] = (_Float16)fmaxf(acc[nt][r], 0.f);

    // ---- GEMM3: A @ W2a -> y fp16 (bias deferred past aggregation) ----
    #pragma unroll
    for (int kt = 0; kt < 4; ++kt) af[kt] = *(const f16x8*)&A[arow][kt * 32 + kq];
    f32x4 ya[3];
    #pragma unroll
    for (int nt = 0; nt < 3; ++nt) ya[nt] = (f32x4){0.f, 0.f, 0.f, 0.f};
    #pragma unroll
    for (int nt = 0; nt < 3; ++nt)
        #pragma unroll
        for (int kt = 0; kt < 4; ++kt) {
            f16x8 bf = *(const f16x8*)(Pc + ((size_t)(kt * 3 + nt) * 64 + l) * 8);
            ya[nt] = __builtin_amdgcn_mfma_f32_16x16x32_f16(af[kt], bf, ya[nt], 0, 0, 0);
        }
    #pragma unroll
    for (int nt = 0; nt < 3; ++nt) {
        int col = nt * 16 + ccol;
        if (col < NC) {
            #pragma unroll
            for (int r = 0; r < 4; ++r) {
                size_t gr = row0 + crow + r;
                if (gr < N_NODES) y[gr * NC + col] = __float2half(ya[nt][r]);
            }
        }
    }
}

// ---------------- z = y + segsum(y[src]); h2 = relu(z+b2a); out = softmax(h2@W2b+b2b) -------------
__device__ __forceinline__ void acc_row8(float* acc, uint4 v) {
    __half2 h;
    float2 f;
    *(unsigned*)&h = v.x; f = __half22float2(h); acc[0] += f.x; acc[1] += f.y;
    *(unsigned*)&h = v.y; f = __half22float2(h); acc[2] += f.x; acc[3] += f.y;
    *(unsigned*)&h = v.z; f = __half22float2(h); acc[4] += f.x; acc[5] += f.y;
    *(unsigned*)&h = v.w; f = __half22float2(h); acc[6] += f.x; acc[7] += f.y;
}

__global__ __launch_bounds__(256) void k_gather2(const __half* __restrict__ y, const int* __restrict__ rp,
                                                 const int* __restrict__ csr, const float* __restrict__ b2a,
                                                 const float* __restrict__ W2b, const float* __restrict__ b2b,
                                                 float* __restrict__ out) {
    __shared__ float h2s[4][NC];
    int l = threadIdx.x & 63, wid = threadIdx.x >> 6;
    int n = blockIdx.x * 4 + wid;
    int g = l / 5, j = l - g * 5;
    const uint4* y4 = (const uint4*)y;

    float acc[8] = {0.f, 0.f, 0.f, 0.f, 0.f, 0.f, 0.f, 0.f};
    uint4 self;
    if (l < 5) self = y4[(size_t)n * 5 + j];

    int i0 = rp[n], e = rp[n + 1];
    int niter = (e - i0 + 11) / 12;
    uint4 cur;
    if (niter > 0) {
        int idx = i0 + g;
        int s = (g < 12 && idx < e) ? csr[idx] : N_NODES;
        cur = y4[(size_t)s * 5 + j];
    }
    for (int k = 1; k < niter; ++k) {
        int idx = i0 + k * 12 + g;
        int s = (g < 12 && idx < e) ? csr[idx] : N_NODES;
        uint4 nxt = y4[(size_t)s * 5 + j];
        acc_row8(acc, cur);
        cur = nxt;
    }
    if (niter > 0) acc_row8(acc, cur);
    if (l < 5) acc_row8(acc, self);

    #pragma unroll
    for (int k = 0; k < 8; ++k) acc[k] += __shfl_down(acc[k], 30);
    #pragma unroll
    for (int k = 0; k < 8; ++k) acc[k] += __shfl_down(acc[k], 15);
    #pragma unroll
    for (int k = 0; k < 8; ++k) acc[k] += __shfl_down(acc[k], 5) + __shfl_down(acc[k], 10);

    if (l < 5) {
        float4 b0 = *(const float4*)(b2a + 8 * l);
        float4 b1 = *(const float4*)(b2a + 8 * l + 4);
        float4 h0, h1;
        h0.x = fmaxf(acc[0] + b0.x, 0.f); h0.y = fmaxf(acc[1] + b0.y, 0.f);
        h0.z = fmaxf(acc[2] + b0.z, 0.f); h0.w = fmaxf(acc[3] + b0.w, 0.f);
        h1.x = fmaxf(acc[4] + b1.x, 0.f); h1.y = fmaxf(acc[5] + b1.y, 0.f);
        h1.z = fmaxf(acc[6] + b1.z, 0.f); h1.w = fmaxf(acc[7] + b1.w, 0.f);
        *(float4*)&h2s[wid][8 * l] = h0;
        *(float4*)&h2s[wid][8 * l + 4] = h1;
    }
    __threadfence_block();

    float logit = -__builtin_inff();
    if (l < NC) {
        float a = b2b[l];
        #pragma unroll 4
        for (int k = 0; k < NC; ++k) a += h2s[wid][k] * W2b[k * NC + l];
        logit = a;
    }
    float m = logit;
    #pragma unroll
    for (int d = 32; d >= 1; d >>= 1) m = fmaxf(m, __shfl_xor(m, d, 64));
    float ev = (l < NC) ? __expf(logit - m) : 0.f;
    float s = ev;
    #pragma unroll
    for (int d = 32; d >= 1; d >>= 1) s += __shfl_xor(s, d, 64);
    if (l < NC) out[(size_t)n * NC + l] = ev / s;
}

extern "C" void kernel_launch(void* const* d_in, const int* in_sizes, int n_in,
                              void* d_out, int out_size, void* d_ws, size_t ws_size,
                              hipStream_t stream) {
    const float* x   = (const float*)d_in[0];
    const int2*  ei  = (const int2*)d_in[1];
    const float* W1a = (const float*)d_in[2];
    const float* b1a = (const float*)d_in[3];
    const float* W1b = (const float*)d_in[4];
    const float* b1b = (const float*)d_in[5];
    const float* W2a = (const float*)d_in[6];
    const float* b2a = (const float*)d_in[7];
    const float* W2b = (const float*)d_in[8];
    const float* b2b = (const float*)d_in[9];
    float* out = (float*)d_out;

    char* w = (char*)d_ws;
    int*    deg  = (int*)(w + 0);             // 100001 ints (raw histogram; zeroed by memset)
    int*    rp   = (int*)(w + 400128);        // 100001 ints (row_ptr, written by k_scan)
    int*    bcur = (int*)(w + 800256);        // 782 ints (bucket cursors)
    int*    csr  = (int*)(w + 803392);        // 1.6M ints (src grouped by dst)
    int*    stg  = (int*)(w + 7203392);       // 1.6M ints (bucket-grouped packed edges)
    __half* xh   = (__half*)(w + 13603392);   // (100000+1)x128 fp16 (incl. zero row)
    __half* y    = (__half*)(w + 39203648);   // (100000+1)x40 fp16 (incl. zero row)
    _Float16* Pa = (_Float16*)(w + 47203776); // 32KB W1a frags
    _Float16* Pb = (_Float16*)(w + 47236544); // 32KB W1b frags
    _Float16* Pc = (_Float16*)(w + 47269312); // 12KB W2a frags
    // total ws needed: 47,281,600 bytes

    (void)hipMemsetAsync(deg, 0, 400004, stream);
    k_hist_cvt <<<N_EDGES / 256 + 19, 256, 0, stream>>>(ei, deg, x, xh, y, W1a, W1b, W2a, Pa, Pb, Pc);
    k_scan     <<<SCAN_NB, SCAN_T, 0, stream>>>(deg, rp, bcur);
    k_binfill  <<<NBLK_FILL, 256, 0, stream>>>(ei, bcur, stg);
    k_csr_local<<<NBUCKET, 256, 0, stream>>>(rp, stg, csr);
    k_gmlp     <<<(N_NODES + 63) / 64, 256, 0, stream>>>(xh, rp, csr, Pa, Pb, Pc, b1a, b1b, y);
    k_gather2  <<<N_NODES / 4, 256, 0, stream>>>(y, rp, csr, b2a, W2b, b2b, out);
}